// Round 7
// baseline (936.057 us; speedup 1.0000x reference)
//
#include <hip/hip_runtime.h>
#include <hip/hip_bf16.h>
#include <math.h>

#define B_   2
#define N_   4096
#define D_   1024
#define DS_  1024
#define HID_ 4096
#define ROWS (B_ * N_)   // 8192

#define CHK 128   // scan chunks per batch
#define TCH 32    // timesteps per chunk

typedef __attribute__((ext_vector_type(8))) short bf16x8;
typedef __attribute__((ext_vector_type(4))) float f32x4;

#define ASG __attribute__((address_space(1)))
#define AS3 __attribute__((address_space(3)))

__device__ __forceinline__ float bf2f(unsigned short u) {
  union { float f; unsigned int i; } v; v.i = ((unsigned int)u) << 16; return v.f;
}
__device__ __forceinline__ unsigned short f2bf(float f) {
  union { float f; unsigned int i; } v; v.f = f;
  unsigned int r = v.i + 0x7fffu + ((v.i >> 16) & 1u);
  return (unsigned short)(r >> 16);
}

// ---------------- prep: column-means of state_w, mean of state_b ----------------
__global__ void means_kernel(const float* __restrict__ W, const float* __restrict__ bvec,
                             float* __restrict__ swmean, float* __restrict__ sbmean) {
  __shared__ float sm[4];
  int bid = blockIdx.x, t = threadIdx.x;
  const float* src = (bid < D_) ? (W + (size_t)bid * DS_) : bvec;
  float s = 0.f;
  for (int j = t; j < DS_; j += 256) s += src[j];
  for (int o = 32; o; o >>= 1) s += __shfl_down(s, o);
  if ((t & 63) == 0) sm[t >> 6] = s;
  __syncthreads();
  if (t == 0) {
    float r = (sm[0] + sm[1] + sm[2] + sm[3]) * (1.f / DS_);
    if (bid < D_) swmean[bid] = r; else sbmean[0] = r;
  }
}

// ---------------- prep: all five W (KxN fp32) -> WT (NxK bf16) in ONE launch ----------------
__global__ void transpose_all_kernel(const float* __restrict__ gw, const float* __restrict__ sw,
                                     const float* __restrict__ ow, const float* __restrict__ w1,
                                     const float* __restrict__ w2,
                                     unsigned short* __restrict__ gwT, unsigned short* __restrict__ swT,
                                     unsigned short* __restrict__ owT, unsigned short* __restrict__ w1T,
                                     unsigned short* __restrict__ w2T) {
  __shared__ float tile[32][33];
  int b = blockIdx.x;
  const float* W; unsigned short* WT; int K, N, t0;
  if (b < 2048)      { W = gw; WT = gwT; K = 1024; N = 2048; t0 = b; }
  else if (b < 3072) { W = sw; WT = swT; K = 1024; N = 1024; t0 = b - 2048; }
  else if (b < 4096) { W = ow; WT = owT; K = 1024; N = 1024; t0 = b - 3072; }
  else if (b < 8192) { W = w1; WT = w1T; K = 1024; N = 4096; t0 = b - 4096; }
  else               { W = w2; WT = w2T; K = 4096; N = 1024; t0 = b - 8192; }
  int ntx = N >> 5;
  int bn = (t0 % ntx) * 32, bk = (t0 / ntx) * 32;
  int tx = threadIdx.x & 31, ty = threadIdx.x >> 5; // 32x8
  for (int i = ty; i < 32; i += 8)
    tile[i][tx] = W[(size_t)(bk + i) * N + bn + tx];
  __syncthreads();
  for (int i = ty; i < 32; i += 8)
    WT[(size_t)(bn + i) * K + bk + tx] = f2bf(tile[tx][i]);
}

// ---------------- LayerNorm (fp32 or bf16 input; optional fused delta) ----------------
template<bool WITH_DELTA, bool BF16IN>
__global__ void ln_kernel(const void* __restrict__ xin, const float* __restrict__ w,
                          const float* __restrict__ bb, unsigned short* __restrict__ out_bf,
                          const float* __restrict__ swmean, const float* __restrict__ sbmean,
                          float* __restrict__ delta, float* __restrict__ ea) {
  __shared__ float sm[8];
  __shared__ float bc[2];
  int row = blockIdx.x, t = threadIdx.x;
  float x0, x1, x2, x3;
  if (BF16IN) {
    const unsigned short* xr = (const unsigned short*)xin + (size_t)row * D_;
    ushort4 xv = ((const ushort4*)xr)[t];
    x0 = bf2f(xv.x); x1 = bf2f(xv.y); x2 = bf2f(xv.z); x3 = bf2f(xv.w);
  } else {
    const float* xr = (const float*)xin + (size_t)row * D_;
    float4 xv = ((const float4*)xr)[t];
    x0 = xv.x; x1 = xv.y; x2 = xv.z; x3 = xv.w;
  }
  float s  = x0 + x1 + x2 + x3;
  float sq = x0 * x0 + x1 * x1 + x2 * x2 + x3 * x3;
  for (int o = 32; o; o >>= 1) { s += __shfl_down(s, o); sq += __shfl_down(sq, o); }
  if ((t & 63) == 0) { sm[t >> 6] = s; sm[4 + (t >> 6)] = sq; }
  __syncthreads();
  if (t == 0) {
    float ts = sm[0] + sm[1] + sm[2] + sm[3];
    float tq = sm[4] + sm[5] + sm[6] + sm[7];
    float mu = ts * (1.f / D_);
    float var = tq * (1.f / D_) - mu * mu;
    bc[0] = mu; bc[1] = rsqrtf(var + 1e-5f);
  }
  __syncthreads();
  float mu = bc[0], rs = bc[1];
  float4 wv = ((const float4*)w)[t];
  float4 bv = ((const float4*)bb)[t];
  float n0 = (x0 - mu) * rs * wv.x + bv.x;
  float n1 = (x1 - mu) * rs * wv.y + bv.y;
  float n2 = (x2 - mu) * rs * wv.z + bv.z;
  float n3 = (x3 - mu) * rs * wv.w + bv.w;
  ushort4 o4; o4.x = f2bf(n0); o4.y = f2bf(n1); o4.z = f2bf(n2); o4.w = f2bf(n3);
  ((ushort4*)(out_bf + (size_t)row * D_))[t] = o4;
  if (WITH_DELTA) {
    float4 sw = ((const float4*)swmean)[t];
    float d = n0 * sw.x + n1 * sw.y + n2 * sw.z + n3 * sw.w;
    for (int o = 32; o; o >>= 1) d += __shfl_down(d, o);
    if ((t & 63) == 0) sm[t >> 6] = d;
    __syncthreads();
    if (t == 0) {
      float z = sm[0] + sm[1] + sm[2] + sm[3] + sbmean[0];
      float dl = (z > 15.f) ? z : log1pf(__expf(z));
      delta[row] = dl;
      ea[row] = __expf(-dl);
    }
  }
}

// ---------------- 8-phase 256-wide MFMA GEMM, BK=64 (r2-proven) ----------------
// EPI: 1 silu->bf16, 2 ->bf16, 3 +res(f32)->f32, 4 gelu->bf16, 6 +res(f32)->bf16, 7 +res(bf16)->f32

#define BARX { __builtin_amdgcn_s_barrier(); __builtin_amdgcn_sched_barrier(0); }

#define RD_A(TAU, H) { const char* ab_ = smem + ((((TAU)&1)*2+(H))<<14); \
  _Pragma("unroll") for (int mm_ = 0; mm_ < MB_H; ++mm_) \
  _Pragma("unroll") for (int ks_ = 0; ks_ < 2; ++ks_) { \
    int r_ = wr*(16*MB_H) + mm_*16 + l15; \
    int by_ = r_*128 + ks_*64 + kq16; by_ ^= ((by_>>7)&7)<<4; \
    af[mm_][ks_] = *(const bf16x8*)(ab_ + by_); } }

#define RD_B(TAU, H, DST) { const char* bb_ = smemB + ((((TAU)&1)*2+(H)))*SB; \
  _Pragma("unroll") for (int nn_ = 0; nn_ < NB_H; ++nn_) \
  _Pragma("unroll") for (int ks_ = 0; ks_ < 2; ++ks_) { \
    int r_ = wc*(16*NB_H) + nn_*16 + l15; \
    int by_ = r_*128 + ks_*64 + kq16; by_ ^= ((by_>>7)&7)<<4; \
    DST[nn_][ks_] = *(const bf16x8*)(bb_ + by_); } }

#define MFMAQ(QA, QB, BF) { __builtin_amdgcn_s_setprio(1); \
  _Pragma("unroll") for (int m_ = 0; m_ < MB_H; ++m_) \
  _Pragma("unroll") for (int n_ = 0; n_ < NB_H; ++n_) \
  _Pragma("unroll") for (int k_ = 0; k_ < 2; ++k_) \
    acc[(QA)*MB_H+m_][(QB)*NB_H+n_] = __builtin_amdgcn_mfma_f32_16x16x32_bf16( \
        af[m_][k_], BF[n_][k_], acc[(QA)*MB_H+m_][(QB)*NB_H+n_], 0, 0, 0); \
  __builtin_amdgcn_s_setprio(0); }

template<int EPI>
__device__ __forceinline__ void epi_store(float v, size_t off, void* Cout, const float* res) {
  if (EPI == 1) {
    v = v / (1.f + __expf(-v));
    ((unsigned short*)Cout)[off] = f2bf(v);
  } else if (EPI == 2) {
    ((unsigned short*)Cout)[off] = f2bf(v);
  } else if (EPI == 3) {
    ((float*)Cout)[off] = v + res[off];
  } else if (EPI == 4) {
    float tt = v * (0.7978845608f + 0.0356774081f * v * v);
    v = v / (1.f + __expf(-2.f * tt));   // 0.5 v (1+tanh(tt))
    ((unsigned short*)Cout)[off] = f2bf(v);
  } else if (EPI == 6) {
    ((unsigned short*)Cout)[off] = f2bf(v + res[off]);
  } else if (EPI == 7) {
    ((float*)Cout)[off] = v + bf2f(((const unsigned short*)res)[off]);
  }
}

template<int BN, int EPI>
__global__ __launch_bounds__(512, 2) void gemm8p(
    const unsigned short* __restrict__ A1p, int lda1, int M1,
    const unsigned short* __restrict__ A2p, int lda2,
    const unsigned short* __restrict__ BT, const float* __restrict__ bias,
    void* __restrict__ Cout, const float* __restrict__ res,
    int N, int K, int nbx) {
  constexpr int WN   = (BN == 256) ? 4 : 2;
  constexpr int MB_H = (BN == 256) ? 4 : 2;   // m-blocks per wave per A-half
  constexpr int NB_H = 2;                     // n-blocks per wave per B-half
  constexpr int MF   = 2 * MB_H;
  constexpr int LB   = BN / 128;              // global_load_lds per B-half per thread
  constexpr int SB   = (BN / 2) * 64 * 2;     // bytes per B half-slot
  __shared__ char smem[65536 + 4 * SB];       // A: 4 x 16KB, then B: 4 x SB
  char* smemB = smem + 65536;

  const int nwg = gridDim.x;                  // multiple of 8
  int bid = blockIdx.x;
  int wg = (bid & 7) * (nwg >> 3) + (bid >> 3);   // bijective XCD swizzle
  const int bx = wg % nbx, by = wg / nbx;
  const int mbase = by * 256, nbase = bx * BN;

  const int tid = threadIdx.x;
  const int lane = tid & 63, wid = tid >> 6;
  const int wr = wid / WN, wc = wid % WN;
  const int l15 = lane & 15, kq16 = (lane >> 4) * 16;
  const int wvoff16 = wid << 10;

  const unsigned short* Ause; int ldaU;
  if (mbase < M1) { Ause = A1p + (size_t)mbase * lda1; ldaU = lda1; }
  else            { Ause = A2p + (size_t)(mbase - M1) * lda2; ldaU = lda2; }

  // staging: linear LDS dest (l*8KB + tid*16) <- inverse-swizzled global source
  int L0 = tid * 16;        int b0 = L0 ^ (((L0 >> 7) & 7) << 4);
  int L1 = 8192 + tid * 16; int b1 = L1 ^ (((L1 >> 7) & 7) << 4);
  const unsigned short* pA0 = Ause + (size_t)(b0 >> 7) * ldaU + ((b0 & 127) >> 1);
  const unsigned short* pA1 = Ause + (size_t)(b1 >> 7) * ldaU + ((b1 & 127) >> 1);
  const unsigned short* pB0 = BT + (size_t)(nbase + (b0 >> 7)) * K + ((b0 & 127) >> 1);
  const unsigned short* pB1 = BT + (size_t)(nbase + (b1 >> 7)) * K + ((b1 & 127) >> 1);

  auto stageA = [&](int tau, int h, bool en) {
    if (!en) return;
    char* l0 = smem + (((tau & 1) * 2 + h) << 14) + wvoff16;
    const unsigned short* g0 = pA0 + (size_t)h * 128 * ldaU + tau * 64;
    const unsigned short* g1 = pA1 + (size_t)h * 128 * ldaU + tau * 64;
    __builtin_amdgcn_global_load_lds((const ASG void*)g0, (AS3 void*)l0, 16, 0, 0);
    __builtin_amdgcn_global_load_lds((const ASG void*)g1, (AS3 void*)(l0 + 8192), 16, 0, 0);
  };
  auto stageB = [&](int tau, int h, bool en) {
    if (!en) return;
    char* l0 = smemB + ((tau & 1) * 2 + h) * SB + wvoff16;
    const unsigned short* g0 = pB0 + (size_t)h * (BN / 2) * K + tau * 64;
    __builtin_amdgcn_global_load_lds((const ASG void*)g0, (AS3 void*)l0, 16, 0, 0);
    if constexpr (LB == 2) {
      const unsigned short* g1 = pB1 + (size_t)h * (BN / 2) * K + tau * 64;
      __builtin_amdgcn_global_load_lds((const ASG void*)g1, (AS3 void*)(l0 + 8192), 16, 0, 0);
    }
  };
  auto vm_steady = [&]() {
    if constexpr (BN == 256) { asm volatile("s_waitcnt vmcnt(6)" ::: "memory"); }
    else                     { asm volatile("s_waitcnt vmcnt(5)" ::: "memory"); }
  };

  f32x4 acc[MF][4];
#pragma unroll
  for (int m = 0; m < MF; ++m)
#pragma unroll
    for (int n = 0; n < 4; ++n) acc[m][n] = (f32x4){0.f, 0.f, 0.f, 0.f};
  bf16x8 af[MB_H][2], bq0[NB_H][2], bq1[NB_H][2];

  const int NT = K >> 6, NI = NT >> 1;

  // prologue
  stageA(0, 0, true); stageB(0, 0, true); stageA(0, 1, true); stageB(0, 1, true);
  stageA(1, 0, true); stageB(1, 0, true); stageA(1, 1, true);
  vm_steady();
  BARX;

#pragma unroll 1
  for (int i = 0; i < NI; ++i) {
    const int t0 = 2 * i;
    const bool st = (i < NI - 1);
    stageB(t0 + 1, 1, true); RD_A(t0, 0); RD_B(t0, 0, bq0);
    BARX; MFMAQ(0, 0, bq0); BARX;
    stageA(t0 + 2, 0, st); RD_B(t0, 1, bq1);
    BARX; MFMAQ(0, 1, bq1); BARX;
    stageB(t0 + 2, 0, st); RD_A(t0, 1);
    BARX; MFMAQ(1, 1, bq1); BARX;
    stageA(t0 + 2, 1, st);
    if (st) { vm_steady(); } else { asm volatile("s_waitcnt vmcnt(0)" ::: "memory"); }
    BARX; MFMAQ(1, 0, bq0); BARX;
    stageB(t0 + 2, 1, st); RD_A(t0 + 1, 0); RD_B(t0 + 1, 0, bq0);
    BARX; MFMAQ(0, 0, bq0); BARX;
    stageA(t0 + 3, 0, st); RD_B(t0 + 1, 1, bq1);
    BARX; MFMAQ(0, 1, bq1); BARX;
    stageB(t0 + 3, 0, st); RD_A(t0 + 1, 1);
    BARX; MFMAQ(1, 1, bq1); BARX;
    stageA(t0 + 3, 1, st);
    if (st) vm_steady();
    BARX; MFMAQ(1, 0, bq0); BARX;
  }

  // epilogue (scalar, r2-proven)
  const int r0 = (lane >> 4) * 4;
#pragma unroll
  for (int mb = 0; mb < MF; ++mb) {
    int row = mbase + wr * (16 * MB_H) + (mb % MB_H) * 16 + (mb / MB_H) * 128 + r0;
#pragma unroll
    for (int nb = 0; nb < 4; ++nb) {
      int col = nbase + wc * (16 * NB_H) + (nb % NB_H) * 16 + (nb / NB_H) * (BN / 2) + l15;
      float bc = bias[col];
#pragma unroll
      for (int r = 0; r < 4; ++r)
        epi_store<EPI>(acc[mb][nb][r] + bc, (size_t)(row + r) * N + col, Cout, res);
    }
  }
}

// ---------------- BK=32 variant: 64KB LDS -> 2 blocks/CU (mlp1 experiment) ----------------
// BN=256 only. Swizzle for 64B rows: by ^= ((by>>7)&3)<<4  (16-lane col read = 2-way, free).

#define RD_A32(TAU, H) { const char* ab_ = smem + ((((TAU)&1)*2+(H))<<13); \
  _Pragma("unroll") for (int mm_ = 0; mm_ < 4; ++mm_) { \
    int r_ = wr*64 + mm_*16 + l15; \
    int by_ = r_*64 + kq16; by_ ^= ((by_>>7)&3)<<4; \
    af[mm_] = *(const bf16x8*)(ab_ + by_); } }

#define RD_B32(TAU, H, DST) { const char* bb_ = smemB + ((((TAU)&1)*2+(H))<<13); \
  _Pragma("unroll") for (int nn_ = 0; nn_ < 2; ++nn_) { \
    int r_ = wc*32 + nn_*16 + l15; \
    int by_ = r_*64 + kq16; by_ ^= ((by_>>7)&3)<<4; \
    DST[nn_] = *(const bf16x8*)(bb_ + by_); } }

#define MFMAQ32(QA, QB, BF) { __builtin_amdgcn_s_setprio(1); \
  _Pragma("unroll") for (int m_ = 0; m_ < 4; ++m_) \
  _Pragma("unroll") for (int n_ = 0; n_ < 2; ++n_) \
    acc[(QA)*4+m_][(QB)*2+n_] = __builtin_amdgcn_mfma_f32_16x16x32_bf16( \
        af[m_], BF[n_], acc[(QA)*4+m_][(QB)*2+n_], 0, 0, 0); \
  __builtin_amdgcn_s_setprio(0); }

template<int EPI>
__global__ __launch_bounds__(512, 4) void gemm8p32(
    const unsigned short* __restrict__ A1p, int lda1,
    const unsigned short* __restrict__ BT, const float* __restrict__ bias,
    void* __restrict__ Cout, const float* __restrict__ res,
    int N, int K, int nbx) {
  __shared__ char smem[65536];          // A: 4x8KB @0, B: 4x8KB @32KB
  char* smemB = smem + 32768;
  const int nwg = gridDim.x;
  int bid = blockIdx.x;
  int wg = (bid & 7) * (nwg >> 3) + (bid >> 3);
  const int bx = wg % nbx, by = wg / nbx;
  const int mbase = by * 256, nbase = bx * 256;
  const int tid = threadIdx.x;
  const int lane = tid & 63, wid = tid >> 6;
  const int wr = wid >> 2, wc = wid & 3;
  const int l15 = lane & 15, kq16 = (lane >> 4) * 16;

  const unsigned short* Ause = A1p + (size_t)mbase * lda1;
  int L0 = tid * 16; int b0 = L0 ^ (((L0 >> 7) & 3) << 4);
  const unsigned short* pA0 = Ause + (size_t)(b0 >> 6) * lda1 + ((b0 & 63) >> 1);
  const unsigned short* pB0 = BT + (size_t)(nbase + (b0 >> 6)) * K + ((b0 & 63) >> 1);

  auto stageA = [&](int tau, int h, bool en) {
    if (!en) return;
    char* l0 = smem + (((tau & 1) * 2 + h) << 13) + tid * 16;
    const unsigned short* g0 = pA0 + (size_t)h * 128 * lda1 + tau * 32;
    __builtin_amdgcn_global_load_lds((const ASG void*)g0, (AS3 void*)l0, 16, 0, 0);
  };
  auto stageB = [&](int tau, int h, bool en) {
    if (!en) return;
    char* l0 = smemB + (((tau & 1) * 2 + h) << 13) + tid * 16;
    const unsigned short* g0 = pB0 + (size_t)h * 128 * K + tau * 32;
    __builtin_amdgcn_global_load_lds((const ASG void*)g0, (AS3 void*)l0, 16, 0, 0);
  };

  f32x4 acc[8][4];
#pragma unroll
  for (int m = 0; m < 8; ++m)
#pragma unroll
    for (int n = 0; n < 4; ++n) acc[m][n] = (f32x4){0.f, 0.f, 0.f, 0.f};
  bf16x8 af[4], bq0[2], bq1[2];

  const int NT = K >> 5, NI = NT >> 1;

  stageA(0, 0, true); stageB(0, 0, true); stageA(0, 1, true); stageB(0, 1, true);
  stageA(1, 0, true); stageB(1, 0, true); stageA(1, 1, true);
  asm volatile("s_waitcnt vmcnt(3)" ::: "memory");
  BARX;

#pragma unroll 1
  for (int i = 0; i < NI; ++i) {
    const int t0 = 2 * i;
    const bool st = (i < NI - 1);
    stageB(t0 + 1, 1, true); RD_A32(t0, 0); RD_B32(t0, 0, bq0);
    BARX; MFMAQ32(0, 0, bq0); BARX;
    stageA(t0 + 2, 0, st); RD_B32(t0, 1, bq1);
    BARX; MFMAQ32(0, 1, bq1); BARX;
    stageB(t0 + 2, 0, st); RD_A32(t0, 1);
    BARX; MFMAQ32(1, 1, bq1); BARX;
    stageA(t0 + 2, 1, st);
    if (st) { asm volatile("s_waitcnt vmcnt(3)" ::: "memory"); }
    else    { asm volatile("s_waitcnt vmcnt(0)" ::: "memory"); }
    BARX; MFMAQ32(1, 0, bq0); BARX;
    stageB(t0 + 2, 1, st); RD_A32(t0 + 1, 0); RD_B32(t0 + 1, 0, bq0);
    BARX; MFMAQ32(0, 0, bq0); BARX;
    stageA(t0 + 3, 0, st); RD_B32(t0 + 1, 1, bq1);
    BARX; MFMAQ32(0, 1, bq1); BARX;
    stageB(t0 + 3, 0, st); RD_A32(t0 + 1, 1);
    BARX; MFMAQ32(1, 1, bq1); BARX;
    stageA(t0 + 3, 1, st);
    if (st) { asm volatile("s_waitcnt vmcnt(3)" ::: "memory"); }
    BARX; MFMAQ32(1, 0, bq0); BARX;
  }

  const int r0 = (lane >> 4) * 4;
#pragma unroll
  for (int mb = 0; mb < 8; ++mb) {
    int row = mbase + wr * 64 + (mb % 4) * 16 + (mb / 4) * 128 + r0;
#pragma unroll
    for (int nb = 0; nb < 4; ++nb) {
      int col = nbase + wc * 32 + (nb % 2) * 16 + (nb / 2) * 128 + l15;
      float bc = bias[col];
#pragma unroll
      for (int r = 0; r < 4; ++r)
        epi_store<EPI>(acc[mb][nb][r] + bc, (size_t)(row + r) * N + col, Cout, res);
    }
  }
}

// ---------------- elementwise: xg = xn * silu_gate (first half of gs) ----------------
__global__ void ew_xg_kernel(const unsigned short* __restrict__ xn,
                             const unsigned short* __restrict__ gs,
                             unsigned short* __restrict__ xg) {
  size_t i8 = ((size_t)blockIdx.x * 256 + threadIdx.x) * 8;
  size_t row = i8 >> 10, col = i8 & 1023;
  uint4 xv = *(const uint4*)(xn + i8);
  uint4 gv = *(const uint4*)(gs + row * 2048 + col);
  const unsigned short* xs = (const unsigned short*)&xv;
  const unsigned short* gg = (const unsigned short*)&gv;
  uint4 ov; unsigned short* o = (unsigned short*)&ov;
#pragma unroll
  for (int j = 0; j < 8; ++j) o[j] = f2bf(bf2f(xs[j]) * bf2f(gg[j]));
  *(uint4*)(xg + i8) = ov;
}

// ---------------- chunked selective scan (dbu inline; exp(-delta) precomputed) ----------------
__global__ void scan_a_kernel(const unsigned short* __restrict__ u,
                              const unsigned short* __restrict__ bm,
                              const float* __restrict__ delta,
                              const float* __restrict__ ea,
                              float* __restrict__ hend, float* __restrict__ P) {
  int blk = blockIdx.x;
  int b = blk / CHK, c = blk % CHK;
  int ch = threadIdx.x;
  size_t base = ((size_t)(b * N_ + c * TCH)) * DS_ + ch;
  const float* dp = delta + b * N_ + c * TCH;
  const float* ep = ea + b * N_ + c * TCH;
  float h = 0.f, pa = 1.f;
#pragma unroll 4
  for (int t = 0; t < TCH; ++t) {
    float dl = dp[t], e = ep[t];
    float du = dl * bf2f(u[base + (size_t)t * DS_]) * bf2f(bm[base + (size_t)t * DS_]);
    h = e * h + du;
    pa *= e;
  }
  hend[(size_t)blk * DS_ + ch] = h;
  if (ch == 0) P[blk] = pa;
}

__global__ void scan_combine_kernel(const float* __restrict__ hend, const float* __restrict__ P,
                                    float* __restrict__ carryin) {
  int b = blockIdx.x, ch = threadIdx.x;
  float carry = 0.f;
  for (int c = 0; c < CHK; ++c) {
    size_t o = (size_t)(b * CHK + c) * DS_ + ch;
    carryin[o] = carry;
    carry = P[b * CHK + c] * carry + hend[o];
  }
}

__global__ void scan_b_kernel(const unsigned short* __restrict__ u,
                              const unsigned short* __restrict__ bm,
                              const float* __restrict__ delta,
                              const float* __restrict__ ea,
                              const float* __restrict__ carryin,
                              unsigned short* __restrict__ y) {
  int blk = blockIdx.x;
  int b = blk / CHK, c = blk % CHK;
  int ch = threadIdx.x;
  size_t base = ((size_t)(b * N_ + c * TCH)) * DS_ + ch;
  const float* dp = delta + b * N_ + c * TCH;
  const float* ep = ea + b * N_ + c * TCH;
  float h = carryin[(size_t)blk * DS_ + ch];
#pragma unroll 4
  for (int t = 0; t < TCH; ++t) {
    float dl = dp[t], e = ep[t];
    float du = dl * bf2f(u[base + (size_t)t * DS_]) * bf2f(bm[base + (size_t)t * DS_]);
    h = e * h + du;
    y[base + (size_t)t * DS_] = f2bf(h);
  }
}

// ---------------- host ----------------
extern "C" void kernel_launch(void* const* d_in, const int* in_sizes, int n_in,
                              void* d_out, int out_size, void* d_ws, size_t ws_size,
                              hipStream_t stream) {
  const float* x       = (const float*)d_in[0];
  const float* n1w     = (const float*)d_in[1];
  const float* n1b     = (const float*)d_in[2];
  const float* gate_w  = (const float*)d_in[3];
  const float* gate_b  = (const float*)d_in[4];
  const float* state_w = (const float*)d_in[5];
  const float* state_b = (const float*)d_in[6];
  const float* out_w   = (const float*)d_in[7];
  const float* out_b   = (const float*)d_in[8];
  const float* n2w     = (const float*)d_in[9];
  const float* n2b     = (const float*)d_in[10];
  const float* mlp_w1  = (const float*)d_in[11];
  const float* mlp_b1  = (const float*)d_in[12];
  const float* mlp_w2  = (const float*)d_in[13];
  const float* mlp_b2  = (const float*)d_in[14];
  float* outp = (float*)d_out;

  char* w = (char*)d_ws;
  size_t off = 0;
  auto alloc = [&](size_t bytes) { char* p = w + off; off += (bytes + 255) & ~(size_t)255; return p; };

  unsigned short* gate_wT  = (unsigned short*)alloc((size_t)2048 * 1024 * 2);
  unsigned short* state_wT = (unsigned short*)alloc((size_t)1024 * 1024 * 2);
  unsigned short* out_wT   = (unsigned short*)alloc((size_t)1024 * 1024 * 2);
  unsigned short* w1T      = (unsigned short*)alloc((size_t)4096 * 1024 * 2);
  unsigned short* w2T      = (unsigned short*)alloc((size_t)1024 * 4096 * 2);
  float* swmean  = (float*)alloc(D_ * 4);
  float* sbmean  = (float*)alloc(256);
  float* delta   = (float*)alloc((size_t)ROWS * 4);
  float* eadel   = (float*)alloc((size_t)ROWS * 4);
  float* hend    = (float*)alloc((size_t)B_ * CHK * DS_ * 4);
  float* carryin = (float*)alloc((size_t)B_ * CHK * DS_ * 4);
  float* P       = (float*)alloc((size_t)B_ * CHK * 4);
  unsigned short* xn = (unsigned short*)alloc((size_t)ROWS * D_ * 2);
  unsigned short* gs = (unsigned short*)alloc((size_t)ROWS * HID_ * 2); // gate out; later h1
  unsigned short* xg = (unsigned short*)alloc((size_t)ROWS * D_ * 2);   // aliased by y, then x2
  float* x1f         = (float*)alloc((size_t)ROWS * D_ * 4);            // early: u | bm (bf16)

  unsigned short* h1  = gs;
  unsigned short* y   = xg;
  unsigned short* x2  = xg;
  unsigned short* u   = (unsigned short*)x1f;
  unsigned short* bm  = u + (size_t)ROWS * D_;
  unsigned short* x1b = u;   // bf16 residual stream (16MB); written after u/bm consumed

  // prep
  means_kernel<<<D_ + 1, 256, 0, stream>>>(state_w, state_b, swmean, sbmean);
  transpose_all_kernel<<<12288, 256, 0, stream>>>(gate_w, state_w, out_w, mlp_w1, mlp_w2,
                                                  gate_wT, state_wT, out_wT, w1T, w2T);

  // LN1 + fused delta/exp(-delta)
  ln_kernel<true, false><<<ROWS, 256, 0, stream>>>(x, n1w, n1b, xn, swmean, sbmean, delta, eadel);

  const int BIG = 1 << 30;
  // gate GEMM with fused SiLU: (8192 x 2048 x 1024), 256 wgs
  gemm8p<256, 1><<<256, 512, 0, stream>>>(xn, 1024, BIG, xn, 1024,
                                          gate_wT, gate_b, gs, nullptr, 2048, 1024, 8);
  // xg = xn * silu(gate)
  ew_xg_kernel<<<(ROWS * D_) / 8 / 256, 256, 0, stream>>>(xn, gs, xg);
  // fused [u; Bm] = [xg; gg_silu] @ state_w + b : (16384 x 1024 x 1024), 256 wgs
  gemm8p<256, 2><<<256, 512, 0, stream>>>(xg, 1024, 8192, gs + 1024, 2048,
                                          state_wT, state_b, u, nullptr, 1024, 1024, 4);

  // chunked scan (dbu fused)
  scan_a_kernel<<<B_ * CHK, 1024, 0, stream>>>(u, bm, delta, eadel, hend, P);
  scan_combine_kernel<<<B_, 1024, 0, stream>>>(hend, P, carryin);
  scan_b_kernel<<<B_ * CHK, 1024, 0, stream>>>(u, bm, delta, eadel, carryin, y);

  // ssm_out + residual -> x1b (bf16): (8192 x 1024 x 1024), BN=128 -> 256 wgs
  gemm8p<128, 6><<<256, 512, 0, stream>>>(y, 1024, BIG, y, 1024,
                                          out_wT, out_b, x1b, x, 1024, 1024, 8);
  // LN2 (bf16 input)
  ln_kernel<false, true><<<ROWS, 256, 0, stream>>>(x1b, n2w, n2b, x2, nullptr, nullptr, nullptr, nullptr);
  // MLP up: (8192 x 4096 x 1024) — BK=32 / 2-blocks-per-CU experiment, 512 wgs all resident
  gemm8p32<4><<<512, 512, 0, stream>>>(x2, 1024, w1T, mlp_b1, h1, nullptr, 4096, 1024, 16);
  // MLP down + residual(bf16) -> fp32 out: (8192 x 1024 x 4096), BN=128 -> 256 wgs
  gemm8p<128, 7><<<256, 512, 0, stream>>>(h1, 4096, BIG, h1, 4096,
                                          w2T, mlp_b2, outp, (const float*)x1b, 1024, 4096, 8);
}

// Round 8
// 351.088 us; speedup vs baseline: 2.6662x; 2.6662x over previous
//
#include <hip/hip_runtime.h>
#include <hip/hip_bf16.h>
#include <math.h>

#define B_   2
#define N_   4096
#define D_   1024
#define DS_  1024
#define HID_ 4096
#define ROWS (B_ * N_)   // 8192

#define CHK 128   // scan chunks per batch
#define TCH 32    // timesteps per chunk

typedef __attribute__((ext_vector_type(8))) short bf16x8;
typedef __attribute__((ext_vector_type(4))) float f32x4;

#define ASG __attribute__((address_space(1)))
#define AS3 __attribute__((address_space(3)))

__device__ __forceinline__ float bf2f(unsigned short u) {
  union { float f; unsigned int i; } v; v.i = ((unsigned int)u) << 16; return v.f;
}
__device__ __forceinline__ unsigned short f2bf(float f) {
  union { float f; unsigned int i; } v; v.f = f;
  unsigned int r = v.i + 0x7fffu + ((v.i >> 16) & 1u);
  return (unsigned short)(r >> 16);
}

// ---------------- prep: column-means of state_w, mean of state_b ----------------
__global__ void means_kernel(const float* __restrict__ W, const float* __restrict__ bvec,
                             float* __restrict__ swmean, float* __restrict__ sbmean) {
  __shared__ float sm[4];
  int bid = blockIdx.x, t = threadIdx.x;
  const float* src = (bid < D_) ? (W + (size_t)bid * DS_) : bvec;
  float s = 0.f;
  for (int j = t; j < DS_; j += 256) s += src[j];
  for (int o = 32; o; o >>= 1) s += __shfl_down(s, o);
  if ((t & 63) == 0) sm[t >> 6] = s;
  __syncthreads();
  if (t == 0) {
    float r = (sm[0] + sm[1] + sm[2] + sm[3]) * (1.f / DS_);
    if (bid < D_) swmean[bid] = r; else sbmean[0] = r;
  }
}

// ---------------- prep: all five W (KxN fp32) -> WT (NxK bf16) in ONE launch ----------------
__global__ void transpose_all_kernel(const float* __restrict__ gw, const float* __restrict__ sw,
                                     const float* __restrict__ ow, const float* __restrict__ w1,
                                     const float* __restrict__ w2,
                                     unsigned short* __restrict__ gwT, unsigned short* __restrict__ swT,
                                     unsigned short* __restrict__ owT, unsigned short* __restrict__ w1T,
                                     unsigned short* __restrict__ w2T) {
  __shared__ float tile[32][33];
  int b = blockIdx.x;
  const float* W; unsigned short* WT; int K, N, t0;
  if (b < 2048)      { W = gw; WT = gwT; K = 1024; N = 2048; t0 = b; }
  else if (b < 3072) { W = sw; WT = swT; K = 1024; N = 1024; t0 = b - 2048; }
  else if (b < 4096) { W = ow; WT = owT; K = 1024; N = 1024; t0 = b - 3072; }
  else if (b < 8192) { W = w1; WT = w1T; K = 1024; N = 4096; t0 = b - 4096; }
  else               { W = w2; WT = w2T; K = 4096; N = 1024; t0 = b - 8192; }
  int ntx = N >> 5;
  int bn = (t0 % ntx) * 32, bk = (t0 / ntx) * 32;
  int tx = threadIdx.x & 31, ty = threadIdx.x >> 5; // 32x8
  for (int i = ty; i < 32; i += 8)
    tile[i][tx] = W[(size_t)(bk + i) * N + bn + tx];
  __syncthreads();
  for (int i = ty; i < 32; i += 8)
    WT[(size_t)(bn + i) * K + bk + tx] = f2bf(tile[tx][i]);
}

// ---------------- LayerNorm (fp32 or bf16 input; optional fused delta) ----------------
template<bool WITH_DELTA, bool BF16IN>
__global__ void ln_kernel(const void* __restrict__ xin, const float* __restrict__ w,
                          const float* __restrict__ bb, unsigned short* __restrict__ out_bf,
                          const float* __restrict__ swmean, const float* __restrict__ sbmean,
                          float* __restrict__ delta, float* __restrict__ ea) {
  __shared__ float sm[8];
  __shared__ float bc[2];
  int row = blockIdx.x, t = threadIdx.x;
  float x0, x1, x2, x3;
  if (BF16IN) {
    const unsigned short* xr = (const unsigned short*)xin + (size_t)row * D_;
    ushort4 xv = ((const ushort4*)xr)[t];
    x0 = bf2f(xv.x); x1 = bf2f(xv.y); x2 = bf2f(xv.z); x3 = bf2f(xv.w);
  } else {
    const float* xr = (const float*)xin + (size_t)row * D_;
    float4 xv = ((const float4*)xr)[t];
    x0 = xv.x; x1 = xv.y; x2 = xv.z; x3 = xv.w;
  }
  float s  = x0 + x1 + x2 + x3;
  float sq = x0 * x0 + x1 * x1 + x2 * x2 + x3 * x3;
  for (int o = 32; o; o >>= 1) { s += __shfl_down(s, o); sq += __shfl_down(sq, o); }
  if ((t & 63) == 0) { sm[t >> 6] = s; sm[4 + (t >> 6)] = sq; }
  __syncthreads();
  if (t == 0) {
    float ts = sm[0] + sm[1] + sm[2] + sm[3];
    float tq = sm[4] + sm[5] + sm[6] + sm[7];
    float mu = ts * (1.f / D_);
    float var = tq * (1.f / D_) - mu * mu;
    bc[0] = mu; bc[1] = rsqrtf(var + 1e-5f);
  }
  __syncthreads();
  float mu = bc[0], rs = bc[1];
  float4 wv = ((const float4*)w)[t];
  float4 bv = ((const float4*)bb)[t];
  float n0 = (x0 - mu) * rs * wv.x + bv.x;
  float n1 = (x1 - mu) * rs * wv.y + bv.y;
  float n2 = (x2 - mu) * rs * wv.z + bv.z;
  float n3 = (x3 - mu) * rs * wv.w + bv.w;
  ushort4 o4; o4.x = f2bf(n0); o4.y = f2bf(n1); o4.z = f2bf(n2); o4.w = f2bf(n3);
  ((ushort4*)(out_bf + (size_t)row * D_))[t] = o4;
  if (WITH_DELTA) {
    float4 sw = ((const float4*)swmean)[t];
    float d = n0 * sw.x + n1 * sw.y + n2 * sw.z + n3 * sw.w;
    for (int o = 32; o; o >>= 1) d += __shfl_down(d, o);
    if ((t & 63) == 0) sm[t >> 6] = d;
    __syncthreads();
    if (t == 0) {
      float z = sm[0] + sm[1] + sm[2] + sm[3] + sbmean[0];
      float dl = (z > 15.f) ? z : log1pf(__expf(z));
      delta[row] = dl;
      ea[row] = __expf(-dl);
    }
  }
}

// ---------------- 8-phase 256-wide MFMA GEMM, BK=64 (r2-proven) ----------------
// EPI: 1 silu->bf16, 2 ->bf16, 3 +res(f32)->f32, 4 gelu->bf16, 6 +res(f32)->bf16, 7 +res(bf16)->f32

#define BARX { __builtin_amdgcn_s_barrier(); __builtin_amdgcn_sched_barrier(0); }

#define RD_A(TAU, H) { const char* ab_ = smem + ((((TAU)&1)*2+(H))<<14); \
  _Pragma("unroll") for (int mm_ = 0; mm_ < MB_H; ++mm_) \
  _Pragma("unroll") for (int ks_ = 0; ks_ < 2; ++ks_) { \
    int r_ = wr*(16*MB_H) + mm_*16 + l15; \
    int by_ = r_*128 + ks_*64 + kq16; by_ ^= ((by_>>7)&7)<<4; \
    af[mm_][ks_] = *(const bf16x8*)(ab_ + by_); } }

#define RD_B(TAU, H, DST) { const char* bb_ = smemB + ((((TAU)&1)*2+(H)))*SB; \
  _Pragma("unroll") for (int nn_ = 0; nn_ < NB_H; ++nn_) \
  _Pragma("unroll") for (int ks_ = 0; ks_ < 2; ++ks_) { \
    int r_ = wc*(16*NB_H) + nn_*16 + l15; \
    int by_ = r_*128 + ks_*64 + kq16; by_ ^= ((by_>>7)&7)<<4; \
    DST[nn_][ks_] = *(const bf16x8*)(bb_ + by_); } }

#define MFMAQ(QA, QB, BF) { __builtin_amdgcn_s_setprio(1); \
  _Pragma("unroll") for (int m_ = 0; m_ < MB_H; ++m_) \
  _Pragma("unroll") for (int n_ = 0; n_ < NB_H; ++n_) \
  _Pragma("unroll") for (int k_ = 0; k_ < 2; ++k_) \
    acc[(QA)*MB_H+m_][(QB)*NB_H+n_] = __builtin_amdgcn_mfma_f32_16x16x32_bf16( \
        af[m_][k_], BF[n_][k_], acc[(QA)*MB_H+m_][(QB)*NB_H+n_], 0, 0, 0); \
  __builtin_amdgcn_s_setprio(0); }

template<int EPI>
__device__ __forceinline__ void epi_store(float v, size_t off, void* Cout, const float* res) {
  if (EPI == 1) {
    v = v / (1.f + __expf(-v));
    ((unsigned short*)Cout)[off] = f2bf(v);
  } else if (EPI == 2) {
    ((unsigned short*)Cout)[off] = f2bf(v);
  } else if (EPI == 3) {
    ((float*)Cout)[off] = v + res[off];
  } else if (EPI == 4) {
    float tt = v * (0.7978845608f + 0.0356774081f * v * v);
    v = v / (1.f + __expf(-2.f * tt));   // 0.5 v (1+tanh(tt))
    ((unsigned short*)Cout)[off] = f2bf(v);
  } else if (EPI == 6) {
    ((unsigned short*)Cout)[off] = f2bf(v + res[off]);
  } else if (EPI == 7) {
    ((float*)Cout)[off] = v + bf2f(((const unsigned short*)res)[off]);
  }
}

template<int BN, int EPI>
__global__ __launch_bounds__(512, 2) void gemm8p(
    const unsigned short* __restrict__ A1p, int lda1, int M1,
    const unsigned short* __restrict__ A2p, int lda2,
    const unsigned short* __restrict__ BT, const float* __restrict__ bias,
    void* __restrict__ Cout, const float* __restrict__ res,
    int N, int K, int nbx) {
  constexpr int WN   = (BN == 256) ? 4 : 2;
  constexpr int MB_H = (BN == 256) ? 4 : 2;   // m-blocks per wave per A-half
  constexpr int NB_H = 2;                     // n-blocks per wave per B-half
  constexpr int MF   = 2 * MB_H;
  constexpr int LB   = BN / 128;              // global_load_lds per B-half per thread
  constexpr int SB   = (BN / 2) * 64 * 2;     // bytes per B half-slot
  __shared__ char smem[65536 + 4 * SB];       // A: 4 x 16KB, then B: 4 x SB
  char* smemB = smem + 65536;

  const int nwg = gridDim.x;                  // multiple of 8
  int bid = blockIdx.x;
  int wg = (bid & 7) * (nwg >> 3) + (bid >> 3);   // bijective XCD swizzle
  const int bx = wg % nbx, by = wg / nbx;
  const int mbase = by * 256, nbase = bx * BN;

  const int tid = threadIdx.x;
  const int lane = tid & 63, wid = tid >> 6;
  const int wr = wid / WN, wc = wid % WN;
  const int l15 = lane & 15, kq16 = (lane >> 4) * 16;
  const int wvoff16 = wid << 10;

  const unsigned short* Ause; int ldaU;
  if (mbase < M1) { Ause = A1p + (size_t)mbase * lda1; ldaU = lda1; }
  else            { Ause = A2p + (size_t)(mbase - M1) * lda2; ldaU = lda2; }

  // staging: linear LDS dest (l*8KB + tid*16) <- inverse-swizzled global source
  int L0 = tid * 16;        int b0 = L0 ^ (((L0 >> 7) & 7) << 4);
  int L1 = 8192 + tid * 16; int b1 = L1 ^ (((L1 >> 7) & 7) << 4);
  const unsigned short* pA0 = Ause + (size_t)(b0 >> 7) * ldaU + ((b0 & 127) >> 1);
  const unsigned short* pA1 = Ause + (size_t)(b1 >> 7) * ldaU + ((b1 & 127) >> 1);
  const unsigned short* pB0 = BT + (size_t)(nbase + (b0 >> 7)) * K + ((b0 & 127) >> 1);
  const unsigned short* pB1 = BT + (size_t)(nbase + (b1 >> 7)) * K + ((b1 & 127) >> 1);

  auto stageA = [&](int tau, int h, bool en) {
    if (!en) return;
    char* l0 = smem + (((tau & 1) * 2 + h) << 14) + wvoff16;
    const unsigned short* g0 = pA0 + (size_t)h * 128 * ldaU + tau * 64;
    const unsigned short* g1 = pA1 + (size_t)h * 128 * ldaU + tau * 64;
    __builtin_amdgcn_global_load_lds((const ASG void*)g0, (AS3 void*)l0, 16, 0, 0);
    __builtin_amdgcn_global_load_lds((const ASG void*)g1, (AS3 void*)(l0 + 8192), 16, 0, 0);
  };
  auto stageB = [&](int tau, int h, bool en) {
    if (!en) return;
    char* l0 = smemB + ((tau & 1) * 2 + h) * SB + wvoff16;
    const unsigned short* g0 = pB0 + (size_t)h * (BN / 2) * K + tau * 64;
    __builtin_amdgcn_global_load_lds((const ASG void*)g0, (AS3 void*)l0, 16, 0, 0);
    if constexpr (LB == 2) {
      const unsigned short* g1 = pB1 + (size_t)h * (BN / 2) * K + tau * 64;
      __builtin_amdgcn_global_load_lds((const ASG void*)g1, (AS3 void*)(l0 + 8192), 16, 0, 0);
    }
  };
  auto vm_steady = [&]() {
    if constexpr (BN == 256) { asm volatile("s_waitcnt vmcnt(6)" ::: "memory"); }
    else                     { asm volatile("s_waitcnt vmcnt(5)" ::: "memory"); }
  };

  f32x4 acc[MF][4];
#pragma unroll
  for (int m = 0; m < MF; ++m)
#pragma unroll
    for (int n = 0; n < 4; ++n) acc[m][n] = (f32x4){0.f, 0.f, 0.f, 0.f};
  bf16x8 af[MB_H][2], bq0[NB_H][2], bq1[NB_H][2];

  const int NT = K >> 6, NI = NT >> 1;

  // prologue
  stageA(0, 0, true); stageB(0, 0, true); stageA(0, 1, true); stageB(0, 1, true);
  stageA(1, 0, true); stageB(1, 0, true); stageA(1, 1, true);
  vm_steady();
  BARX;

#pragma unroll 1
  for (int i = 0; i < NI; ++i) {
    const int t0 = 2 * i;
    const bool st = (i < NI - 1);
    stageB(t0 + 1, 1, true); RD_A(t0, 0); RD_B(t0, 0, bq0);
    BARX; MFMAQ(0, 0, bq0); BARX;
    stageA(t0 + 2, 0, st); RD_B(t0, 1, bq1);
    BARX; MFMAQ(0, 1, bq1); BARX;
    stageB(t0 + 2, 0, st); RD_A(t0, 1);
    BARX; MFMAQ(1, 1, bq1); BARX;
    stageA(t0 + 2, 1, st);
    if (st) { vm_steady(); } else { asm volatile("s_waitcnt vmcnt(0)" ::: "memory"); }
    BARX; MFMAQ(1, 0, bq0); BARX;
    stageB(t0 + 2, 1, st); RD_A(t0 + 1, 0); RD_B(t0 + 1, 0, bq0);
    BARX; MFMAQ(0, 0, bq0); BARX;
    stageA(t0 + 3, 0, st); RD_B(t0 + 1, 1, bq1);
    BARX; MFMAQ(0, 1, bq1); BARX;
    stageB(t0 + 3, 0, st); RD_A(t0 + 1, 1);
    BARX; MFMAQ(1, 1, bq1); BARX;
    stageA(t0 + 3, 1, st);
    if (st) vm_steady();
    BARX; MFMAQ(1, 0, bq0); BARX;
  }

  // epilogue (scalar, r2-proven)
  const int r0 = (lane >> 4) * 4;
#pragma unroll
  for (int mb = 0; mb < MF; ++mb) {
    int row = mbase + wr * (16 * MB_H) + (mb % MB_H) * 16 + (mb / MB_H) * 128 + r0;
#pragma unroll
    for (int nb = 0; nb < 4; ++nb) {
      int col = nbase + wc * (16 * NB_H) + (nb % NB_H) * 16 + (nb / NB_H) * (BN / 2) + l15;
      float bc = bias[col];
#pragma unroll
      for (int r = 0; r < 4; ++r)
        epi_store<EPI>(acc[mb][nb][r] + bc, (size_t)(row + r) * N + col, Cout, res);
    }
  }
}

// ---------------- elementwise: xg = xn * silu_gate (first half of gs) ----------------
__global__ void ew_xg_kernel(const unsigned short* __restrict__ xn,
                             const unsigned short* __restrict__ gs,
                             unsigned short* __restrict__ xg) {
  size_t i8 = ((size_t)blockIdx.x * 256 + threadIdx.x) * 8;
  size_t row = i8 >> 10, col = i8 & 1023;
  uint4 xv = *(const uint4*)(xn + i8);
  uint4 gv = *(const uint4*)(gs + row * 2048 + col);
  const unsigned short* xs = (const unsigned short*)&xv;
  const unsigned short* gg = (const unsigned short*)&gv;
  uint4 ov; unsigned short* o = (unsigned short*)&ov;
#pragma unroll
  for (int j = 0; j < 8; ++j) o[j] = f2bf(bf2f(xs[j]) * bf2f(gg[j]));
  *(uint4*)(xg + i8) = ov;
}

// ---------------- chunked selective scan (dbu inline; exp(-delta) precomputed) ----------------
__global__ void scan_a_kernel(const unsigned short* __restrict__ u,
                              const unsigned short* __restrict__ bm,
                              const float* __restrict__ delta,
                              const float* __restrict__ ea,
                              float* __restrict__ hend, float* __restrict__ P) {
  int blk = blockIdx.x;
  int b = blk / CHK, c = blk % CHK;
  int ch = threadIdx.x;
  size_t base = ((size_t)(b * N_ + c * TCH)) * DS_ + ch;
  const float* dp = delta + b * N_ + c * TCH;
  const float* ep = ea + b * N_ + c * TCH;
  float h = 0.f, pa = 1.f;
#pragma unroll 4
  for (int t = 0; t < TCH; ++t) {
    float dl = dp[t], e = ep[t];
    float du = dl * bf2f(u[base + (size_t)t * DS_]) * bf2f(bm[base + (size_t)t * DS_]);
    h = e * h + du;
    pa *= e;
  }
  hend[(size_t)blk * DS_ + ch] = h;
  if (ch == 0) P[blk] = pa;
}

__global__ void scan_combine_kernel(const float* __restrict__ hend, const float* __restrict__ P,
                                    float* __restrict__ carryin) {
  int b = blockIdx.x >> 2;
  int ch = (blockIdx.x & 3) * 256 + threadIdx.x;
  float carry = 0.f;
  for (int c = 0; c < CHK; ++c) {
    size_t o = (size_t)(b * CHK + c) * DS_ + ch;
    carryin[o] = carry;
    carry = P[b * CHK + c] * carry + hend[o];
  }
}

__global__ void scan_b_kernel(const unsigned short* __restrict__ u,
                              const unsigned short* __restrict__ bm,
                              const float* __restrict__ delta,
                              const float* __restrict__ ea,
                              const float* __restrict__ carryin,
                              unsigned short* __restrict__ y) {
  int blk = blockIdx.x;
  int b = blk / CHK, c = blk % CHK;
  int ch = threadIdx.x;
  size_t base = ((size_t)(b * N_ + c * TCH)) * DS_ + ch;
  const float* dp = delta + b * N_ + c * TCH;
  const float* ep = ea + b * N_ + c * TCH;
  float h = carryin[(size_t)blk * DS_ + ch];
#pragma unroll 4
  for (int t = 0; t < TCH; ++t) {
    float dl = dp[t], e = ep[t];
    float du = dl * bf2f(u[base + (size_t)t * DS_]) * bf2f(bm[base + (size_t)t * DS_]);
    h = e * h + du;
    y[base + (size_t)t * DS_] = f2bf(h);
  }
}

// ---------------- host ----------------
extern "C" void kernel_launch(void* const* d_in, const int* in_sizes, int n_in,
                              void* d_out, int out_size, void* d_ws, size_t ws_size,
                              hipStream_t stream) {
  const float* x       = (const float*)d_in[0];
  const float* n1w     = (const float*)d_in[1];
  const float* n1b     = (const float*)d_in[2];
  const float* gate_w  = (const float*)d_in[3];
  const float* gate_b  = (const float*)d_in[4];
  const float* state_w = (const float*)d_in[5];
  const float* state_b = (const float*)d_in[6];
  const float* out_w   = (const float*)d_in[7];
  const float* out_b   = (const float*)d_in[8];
  const float* n2w     = (const float*)d_in[9];
  const float* n2b     = (const float*)d_in[10];
  const float* mlp_w1  = (const float*)d_in[11];
  const float* mlp_b1  = (const float*)d_in[12];
  const float* mlp_w2  = (const float*)d_in[13];
  const float* mlp_b2  = (const float*)d_in[14];
  float* outp = (float*)d_out;

  char* w = (char*)d_ws;
  size_t off = 0;
  auto alloc = [&](size_t bytes) { char* p = w + off; off += (bytes + 255) & ~(size_t)255; return p; };

  unsigned short* gate_wT  = (unsigned short*)alloc((size_t)2048 * 1024 * 2);
  unsigned short* state_wT = (unsigned short*)alloc((size_t)1024 * 1024 * 2);
  unsigned short* out_wT   = (unsigned short*)alloc((size_t)1024 * 1024 * 2);
  unsigned short* w1T      = (unsigned short*)alloc((size_t)4096 * 1024 * 2);
  unsigned short* w2T      = (unsigned short*)alloc((size_t)1024 * 4096 * 2);
  float* swmean  = (float*)alloc(D_ * 4);
  float* sbmean  = (float*)alloc(256);
  float* delta   = (float*)alloc((size_t)ROWS * 4);
  float* eadel   = (float*)alloc((size_t)ROWS * 4);
  float* hend    = (float*)alloc((size_t)B_ * CHK * DS_ * 4);
  float* carryin = (float*)alloc((size_t)B_ * CHK * DS_ * 4);
  float* P       = (float*)alloc((size_t)B_ * CHK * 4);
  unsigned short* xn = (unsigned short*)alloc((size_t)ROWS * D_ * 2);
  unsigned short* gs = (unsigned short*)alloc((size_t)ROWS * HID_ * 2); // gate out; later h1
  unsigned short* xg = (unsigned short*)alloc((size_t)ROWS * D_ * 2);   // aliased by y, then x2
  float* x1f         = (float*)alloc((size_t)ROWS * D_ * 4);            // early: u | bm (bf16)

  unsigned short* h1  = gs;
  unsigned short* y   = xg;
  unsigned short* x2  = xg;
  unsigned short* u   = (unsigned short*)x1f;
  unsigned short* bm  = u + (size_t)ROWS * D_;
  unsigned short* x1b = u;   // bf16 residual stream (16MB); written after u/bm consumed

  // prep
  means_kernel<<<D_ + 1, 256, 0, stream>>>(state_w, state_b, swmean, sbmean);
  transpose_all_kernel<<<12288, 256, 0, stream>>>(gate_w, state_w, out_w, mlp_w1, mlp_w2,
                                                  gate_wT, state_wT, out_wT, w1T, w2T);

  // LN1 + fused delta/exp(-delta)
  ln_kernel<true, false><<<ROWS, 256, 0, stream>>>(x, n1w, n1b, xn, swmean, sbmean, delta, eadel);

  const int BIG = 1 << 30;
  // gate GEMM with fused SiLU: (8192 x 2048 x 1024), 256 wgs
  gemm8p<256, 1><<<256, 512, 0, stream>>>(xn, 1024, BIG, xn, 1024,
                                          gate_wT, gate_b, gs, nullptr, 2048, 1024, 8);
  // xg = xn * silu(gate)
  ew_xg_kernel<<<(ROWS * D_) / 8 / 256, 256, 0, stream>>>(xn, gs, xg);
  // fused [u; Bm] = [xg; gg_silu] @ state_w + b : (16384 x 1024 x 1024), 256 wgs
  gemm8p<256, 2><<<256, 512, 0, stream>>>(xg, 1024, 8192, gs + 1024, 2048,
                                          state_wT, state_b, u, nullptr, 1024, 1024, 4);

  // chunked scan (dbu fused)
  scan_a_kernel<<<B_ * CHK, 1024, 0, stream>>>(u, bm, delta, eadel, hend, P);
  scan_combine_kernel<<<B_ * 4, 256, 0, stream>>>(hend, P, carryin);
  scan_b_kernel<<<B_ * CHK, 1024, 0, stream>>>(u, bm, delta, eadel, carryin, y);

  // ssm_out + residual -> x1b (bf16): (8192 x 1024 x 1024), BN=128 -> 256 wgs
  gemm8p<128, 6><<<256, 512, 0, stream>>>(y, 1024, BIG, y, 1024,
                                          out_wT, out_b, x1b, x, 1024, 1024, 8);
  // LN2 (bf16 input)
  ln_kernel<false, true><<<ROWS, 256, 0, stream>>>(x1b, n2w, n2b, x2, nullptr, nullptr, nullptr, nullptr);
  // MLP up: (8192 x 4096 x 1024), 512 wgs (proven BK=64 path)
  gemm8p<256, 4><<<512, 512, 0, stream>>>(x2, 1024, BIG, x2, 1024,
                                          w1T, mlp_b1, h1, nullptr, 4096, 1024, 16);
  // MLP down + residual(bf16) -> fp32 out: (8192 x 1024 x 4096), BN=128 -> 256 wgs
  gemm8p<128, 7><<<256, 512, 0, stream>>>(h1, 4096, BIG, h1, 4096,
                                          w2T, mlp_b2, outp, (const float*)x1b, 1024, 4096, 8);
}

// Round 9
// 350.598 us; speedup vs baseline: 2.6699x; 1.0014x over previous
//
#include <hip/hip_runtime.h>
#include <hip/hip_bf16.h>
#include <math.h>

#define B_   2
#define N_   4096
#define D_   1024
#define DS_  1024
#define HID_ 4096
#define ROWS (B_ * N_)   // 8192

#define CHK 128   // scan chunks per batch
#define TCH 32    // timesteps per chunk

typedef __attribute__((ext_vector_type(8))) short bf16x8;
typedef __attribute__((ext_vector_type(4))) float f32x4;

#define ASG __attribute__((address_space(1)))
#define AS3 __attribute__((address_space(3)))

__device__ __forceinline__ float bf2f(unsigned short u) {
  union { float f; unsigned int i; } v; v.i = ((unsigned int)u) << 16; return v.f;
}
__device__ __forceinline__ unsigned short f2bf(float f) {
  union { float f; unsigned int i; } v; v.f = f;
  unsigned int r = v.i + 0x7fffu + ((v.i >> 16) & 1u);
  return (unsigned short)(r >> 16);
}

// ---------------- prep: column-means of state_w, mean of state_b ----------------
__global__ void means_kernel(const float* __restrict__ W, const float* __restrict__ bvec,
                             float* __restrict__ swmean, float* __restrict__ sbmean) {
  __shared__ float sm[4];
  int bid = blockIdx.x, t = threadIdx.x;
  const float* src = (bid < D_) ? (W + (size_t)bid * DS_) : bvec;
  float s = 0.f;
  for (int j = t; j < DS_; j += 256) s += src[j];
  for (int o = 32; o; o >>= 1) s += __shfl_down(s, o);
  if ((t & 63) == 0) sm[t >> 6] = s;
  __syncthreads();
  if (t == 0) {
    float r = (sm[0] + sm[1] + sm[2] + sm[3]) * (1.f / DS_);
    if (bid < D_) swmean[bid] = r; else sbmean[0] = r;
  }
}

// ---------------- prep: all five W (KxN fp32) -> WT (NxK bf16) in ONE launch ----------------
__global__ void transpose_all_kernel(const float* __restrict__ gw, const float* __restrict__ sw,
                                     const float* __restrict__ ow, const float* __restrict__ w1,
                                     const float* __restrict__ w2,
                                     unsigned short* __restrict__ gwT, unsigned short* __restrict__ swT,
                                     unsigned short* __restrict__ owT, unsigned short* __restrict__ w1T,
                                     unsigned short* __restrict__ w2T) {
  __shared__ float tile[32][33];
  int b = blockIdx.x;
  const float* W; unsigned short* WT; int K, N, t0;
  if (b < 2048)      { W = gw; WT = gwT; K = 1024; N = 2048; t0 = b; }
  else if (b < 3072) { W = sw; WT = swT; K = 1024; N = 1024; t0 = b - 2048; }
  else if (b < 4096) { W = ow; WT = owT; K = 1024; N = 1024; t0 = b - 3072; }
  else if (b < 8192) { W = w1; WT = w1T; K = 1024; N = 4096; t0 = b - 4096; }
  else               { W = w2; WT = w2T; K = 4096; N = 1024; t0 = b - 8192; }
  int ntx = N >> 5;
  int bn = (t0 % ntx) * 32, bk = (t0 / ntx) * 32;
  int tx = threadIdx.x & 31, ty = threadIdx.x >> 5; // 32x8
  for (int i = ty; i < 32; i += 8)
    tile[i][tx] = W[(size_t)(bk + i) * N + bn + tx];
  __syncthreads();
  for (int i = ty; i < 32; i += 8)
    WT[(size_t)(bn + i) * K + bk + tx] = f2bf(tile[tx][i]);
}

// ---------------- LayerNorm (fp32 or bf16 input; optional fused delta) ----------------
template<bool WITH_DELTA, bool BF16IN>
__global__ void ln_kernel(const void* __restrict__ xin, const float* __restrict__ w,
                          const float* __restrict__ bb, unsigned short* __restrict__ out_bf,
                          const float* __restrict__ swmean, const float* __restrict__ sbmean,
                          float* __restrict__ delta, float* __restrict__ ea) {
  __shared__ float sm[8];
  __shared__ float bc[2];
  int row = blockIdx.x, t = threadIdx.x;
  float x0, x1, x2, x3;
  if (BF16IN) {
    const unsigned short* xr = (const unsigned short*)xin + (size_t)row * D_;
    ushort4 xv = ((const ushort4*)xr)[t];
    x0 = bf2f(xv.x); x1 = bf2f(xv.y); x2 = bf2f(xv.z); x3 = bf2f(xv.w);
  } else {
    const float* xr = (const float*)xin + (size_t)row * D_;
    float4 xv = ((const float4*)xr)[t];
    x0 = xv.x; x1 = xv.y; x2 = xv.z; x3 = xv.w;
  }
  float s  = x0 + x1 + x2 + x3;
  float sq = x0 * x0 + x1 * x1 + x2 * x2 + x3 * x3;
  for (int o = 32; o; o >>= 1) { s += __shfl_down(s, o); sq += __shfl_down(sq, o); }
  if ((t & 63) == 0) { sm[t >> 6] = s; sm[4 + (t >> 6)] = sq; }
  __syncthreads();
  if (t == 0) {
    float ts = sm[0] + sm[1] + sm[2] + sm[3];
    float tq = sm[4] + sm[5] + sm[6] + sm[7];
    float mu = ts * (1.f / D_);
    float var = tq * (1.f / D_) - mu * mu;
    bc[0] = mu; bc[1] = rsqrtf(var + 1e-5f);
  }
  __syncthreads();
  float mu = bc[0], rs = bc[1];
  float4 wv = ((const float4*)w)[t];
  float4 bv = ((const float4*)bb)[t];
  float n0 = (x0 - mu) * rs * wv.x + bv.x;
  float n1 = (x1 - mu) * rs * wv.y + bv.y;
  float n2 = (x2 - mu) * rs * wv.z + bv.z;
  float n3 = (x3 - mu) * rs * wv.w + bv.w;
  ushort4 o4; o4.x = f2bf(n0); o4.y = f2bf(n1); o4.z = f2bf(n2); o4.w = f2bf(n3);
  ((ushort4*)(out_bf + (size_t)row * D_))[t] = o4;
  if (WITH_DELTA) {
    float4 sw = ((const float4*)swmean)[t];
    float d = n0 * sw.x + n1 * sw.y + n2 * sw.z + n3 * sw.w;
    for (int o = 32; o; o >>= 1) d += __shfl_down(d, o);
    if ((t & 63) == 0) sm[t >> 6] = d;
    __syncthreads();
    if (t == 0) {
      float z = sm[0] + sm[1] + sm[2] + sm[3] + sbmean[0];
      float dl = (z > 15.f) ? z : log1pf(__expf(z));
      delta[row] = dl;
      ea[row] = __expf(-dl);
    }
  }
}

// ---------------- 8-phase 256-wide MFMA GEMM, BK=64 (r2-proven core) ----------------
// EPI: 1 silu->bf16, 2 ->bf16, 3 +res(f32)->f32, 4 gelu->bf16, 6 +res(f32)->bf16,
//      7 +res(bf16)->f32,
//      8 gate-dual: col<1024 -> Cout = silu (gs1); col>=1024 -> Cout2 odd-interleaved silu
//      9 pair-dbu: rows alternate u/bm; Cout[row/2] = res[row/2] * u * bm   (res = delta)

#define BARX { __builtin_amdgcn_s_barrier(); __builtin_amdgcn_sched_barrier(0); }

#define RD_A(TAU, H) { const char* ab_ = smem + ((((TAU)&1)*2+(H))<<14); \
  _Pragma("unroll") for (int mm_ = 0; mm_ < MB_H; ++mm_) \
  _Pragma("unroll") for (int ks_ = 0; ks_ < 2; ++ks_) { \
    int r_ = wr*(16*MB_H) + mm_*16 + l15; \
    int by_ = r_*128 + ks_*64 + kq16; by_ ^= ((by_>>7)&7)<<4; \
    af[mm_][ks_] = *(const bf16x8*)(ab_ + by_); } }

#define RD_B(TAU, H, DST) { const char* bb_ = smemB + ((((TAU)&1)*2+(H)))*SB; \
  _Pragma("unroll") for (int nn_ = 0; nn_ < NB_H; ++nn_) \
  _Pragma("unroll") for (int ks_ = 0; ks_ < 2; ++ks_) { \
    int r_ = wc*(16*NB_H) + nn_*16 + l15; \
    int by_ = r_*128 + ks_*64 + kq16; by_ ^= ((by_>>7)&7)<<4; \
    DST[nn_][ks_] = *(const bf16x8*)(bb_ + by_); } }

#define MFMAQ(QA, QB, BF) { __builtin_amdgcn_s_setprio(1); \
  _Pragma("unroll") for (int m_ = 0; m_ < MB_H; ++m_) \
  _Pragma("unroll") for (int n_ = 0; n_ < NB_H; ++n_) \
  _Pragma("unroll") for (int k_ = 0; k_ < 2; ++k_) \
    acc[(QA)*MB_H+m_][(QB)*NB_H+n_] = __builtin_amdgcn_mfma_f32_16x16x32_bf16( \
        af[m_][k_], BF[n_][k_], acc[(QA)*MB_H+m_][(QB)*NB_H+n_], 0, 0, 0); \
  __builtin_amdgcn_s_setprio(0); }

template<int EPI>
__device__ __forceinline__ void epi_store(float v, size_t off, void* Cout, const float* res) {
  if (EPI == 1) {
    v = v / (1.f + __expf(-v));
    ((unsigned short*)Cout)[off] = f2bf(v);
  } else if (EPI == 2) {
    ((unsigned short*)Cout)[off] = f2bf(v);
  } else if (EPI == 3) {
    ((float*)Cout)[off] = v + res[off];
  } else if (EPI == 4) {
    float tt = v * (0.7978845608f + 0.0356774081f * v * v);
    v = v / (1.f + __expf(-2.f * tt));   // 0.5 v (1+tanh(tt))
    ((unsigned short*)Cout)[off] = f2bf(v);
  } else if (EPI == 6) {
    ((unsigned short*)Cout)[off] = f2bf(v + res[off]);
  } else if (EPI == 7) {
    ((float*)Cout)[off] = v + bf2f(((const unsigned short*)res)[off]);
  }
}

template<int BN, int EPI>
__global__ __launch_bounds__(512, 2) void gemm8p(
    const unsigned short* __restrict__ A1p, int lda1, int M1,
    const unsigned short* __restrict__ A2p, int lda2,
    const unsigned short* __restrict__ BT, const float* __restrict__ bias,
    void* __restrict__ Cout, const float* __restrict__ res,
    int N, int K, int nbx, void* __restrict__ Cout2) {
  constexpr int WN   = (BN == 256) ? 4 : 2;
  constexpr int MB_H = (BN == 256) ? 4 : 2;   // m-blocks per wave per A-half
  constexpr int NB_H = 2;                     // n-blocks per wave per B-half
  constexpr int MF   = 2 * MB_H;
  constexpr int LB   = BN / 128;              // global_load_lds per B-half per thread
  constexpr int SB   = (BN / 2) * 64 * 2;     // bytes per B half-slot
  __shared__ char smem[65536 + 4 * SB];       // A: 4 x 16KB, then B: 4 x SB
  char* smemB = smem + 65536;

  const int nwg = gridDim.x;                  // multiple of 8
  int bid = blockIdx.x;
  int wg = (bid & 7) * (nwg >> 3) + (bid >> 3);   // bijective XCD swizzle
  const int bx = wg % nbx, by = wg / nbx;
  const int mbase = by * 256, nbase = bx * BN;

  const int tid = threadIdx.x;
  const int lane = tid & 63, wid = tid >> 6;
  const int wr = wid / WN, wc = wid % WN;
  const int l15 = lane & 15, kq16 = (lane >> 4) * 16;
  const int wvoff16 = wid << 10;

  const unsigned short* Ause; int ldaU;
  if (mbase < M1) { Ause = A1p + (size_t)mbase * lda1; ldaU = lda1; }
  else            { Ause = A2p + (size_t)(mbase - M1) * lda2; ldaU = lda2; }

  // staging: linear LDS dest (l*8KB + tid*16) <- inverse-swizzled global source
  int L0 = tid * 16;        int b0 = L0 ^ (((L0 >> 7) & 7) << 4);
  int L1 = 8192 + tid * 16; int b1 = L1 ^ (((L1 >> 7) & 7) << 4);
  const unsigned short* pA0 = Ause + (size_t)(b0 >> 7) * ldaU + ((b0 & 127) >> 1);
  const unsigned short* pA1 = Ause + (size_t)(b1 >> 7) * ldaU + ((b1 & 127) >> 1);
  const unsigned short* pB0 = BT + (size_t)(nbase + (b0 >> 7)) * K + ((b0 & 127) >> 1);
  const unsigned short* pB1 = BT + (size_t)(nbase + (b1 >> 7)) * K + ((b1 & 127) >> 1);

  auto stageA = [&](int tau, int h, bool en) {
    if (!en) return;
    char* l0 = smem + (((tau & 1) * 2 + h) << 14) + wvoff16;
    const unsigned short* g0 = pA0 + (size_t)h * 128 * ldaU + tau * 64;
    const unsigned short* g1 = pA1 + (size_t)h * 128 * ldaU + tau * 64;
    __builtin_amdgcn_global_load_lds((const ASG void*)g0, (AS3 void*)l0, 16, 0, 0);
    __builtin_amdgcn_global_load_lds((const ASG void*)g1, (AS3 void*)(l0 + 8192), 16, 0, 0);
  };
  auto stageB = [&](int tau, int h, bool en) {
    if (!en) return;
    char* l0 = smemB + ((tau & 1) * 2 + h) * SB + wvoff16;
    const unsigned short* g0 = pB0 + (size_t)h * (BN / 2) * K + tau * 64;
    __builtin_amdgcn_global_load_lds((const ASG void*)g0, (AS3 void*)l0, 16, 0, 0);
    if constexpr (LB == 2) {
      const unsigned short* g1 = pB1 + (size_t)h * (BN / 2) * K + tau * 64;
      __builtin_amdgcn_global_load_lds((const ASG void*)g1, (AS3 void*)(l0 + 8192), 16, 0, 0);
    }
  };
  auto vm_steady = [&]() {
    if constexpr (BN == 256) { asm volatile("s_waitcnt vmcnt(6)" ::: "memory"); }
    else                     { asm volatile("s_waitcnt vmcnt(5)" ::: "memory"); }
  };

  f32x4 acc[MF][4];
#pragma unroll
  for (int m = 0; m < MF; ++m)
#pragma unroll
    for (int n = 0; n < 4; ++n) acc[m][n] = (f32x4){0.f, 0.f, 0.f, 0.f};
  bf16x8 af[MB_H][2], bq0[NB_H][2], bq1[NB_H][2];

  const int NT = K >> 6, NI = NT >> 1;

  // prologue
  stageA(0, 0, true); stageB(0, 0, true); stageA(0, 1, true); stageB(0, 1, true);
  stageA(1, 0, true); stageB(1, 0, true); stageA(1, 1, true);
  vm_steady();
  BARX;

#pragma unroll 1
  for (int i = 0; i < NI; ++i) {
    const int t0 = 2 * i;
    const bool st = (i < NI - 1);
    stageB(t0 + 1, 1, true); RD_A(t0, 0); RD_B(t0, 0, bq0);
    BARX; MFMAQ(0, 0, bq0); BARX;
    stageA(t0 + 2, 0, st); RD_B(t0, 1, bq1);
    BARX; MFMAQ(0, 1, bq1); BARX;
    stageB(t0 + 2, 0, st); RD_A(t0, 1);
    BARX; MFMAQ(1, 1, bq1); BARX;
    stageA(t0 + 2, 1, st);
    if (st) { vm_steady(); } else { asm volatile("s_waitcnt vmcnt(0)" ::: "memory"); }
    BARX; MFMAQ(1, 0, bq0); BARX;
    stageB(t0 + 2, 1, st); RD_A(t0 + 1, 0); RD_B(t0 + 1, 0, bq0);
    BARX; MFMAQ(0, 0, bq0); BARX;
    stageA(t0 + 3, 0, st); RD_B(t0 + 1, 1, bq1);
    BARX; MFMAQ(0, 1, bq1); BARX;
    stageB(t0 + 3, 0, st); RD_A(t0 + 1, 1);
    BARX; MFMAQ(1, 1, bq1); BARX;
    stageA(t0 + 3, 1, st);
    if (st) vm_steady();
    BARX; MFMAQ(1, 0, bq0); BARX;
  }

  // epilogue (scalar stores, r2-proven pattern; EPI 8/9 are store-redirects only)
  const int r0 = (lane >> 4) * 4;
#pragma unroll
  for (int mb = 0; mb < MF; ++mb) {
    int row = mbase + wr * (16 * MB_H) + (mb % MB_H) * 16 + (mb / MB_H) * 128 + r0;
#pragma unroll
    for (int nb = 0; nb < 4; ++nb) {
      int col = nbase + wc * (16 * NB_H) + (nb % NB_H) * 16 + (nb / NB_H) * (BN / 2) + l15;
      float bc = bias[col];
      if (EPI == 9) {
        // rows alternate u (even) / bm (odd); emit dbu = delta * u * bm (no reads but delta)
#pragma unroll
        for (int pr = 0; pr < 2; ++pr) {
          float e0 = acc[mb][nb][2 * pr] + bc;
          float e1 = acc[mb][nb][2 * pr + 1] + bc;
          int i0 = (row >> 1) + pr;
          ((unsigned short*)Cout)[(size_t)i0 * N + col] = f2bf(res[i0] * e0 * e1);
        }
      } else if (EPI == 8) {
#pragma unroll
        for (int r = 0; r < 4; ++r) {
          float v = acc[mb][nb][r] + bc;
          v = v / (1.f + __expf(-v));
          if (col < 1024)
            ((unsigned short*)Cout)[(size_t)(row + r) * 1024 + col] = f2bf(v);
          else
            ((unsigned short*)Cout2)[(size_t)(2 * (row + r) + 1) * 1024 + (col - 1024)] = f2bf(v);
        }
      } else {
#pragma unroll
        for (int r = 0; r < 4; ++r)
          epi_store<EPI>(acc[mb][nb][r] + bc, (size_t)(row + r) * N + col, Cout, res);
      }
    }
  }
}

// ---------------- elementwise: AI even rows = xn * gs1 ----------------
__global__ void ew_xg_kernel(const unsigned short* __restrict__ xn,
                             const unsigned short* __restrict__ gs1,
                             unsigned short* __restrict__ AI) {
  size_t i8 = ((size_t)blockIdx.x * 256 + threadIdx.x) * 8;
  size_t row = i8 >> 10, col = i8 & 1023;
  uint4 xv = *(const uint4*)(xn + i8);
  uint4 gv = *(const uint4*)(gs1 + i8);
  const unsigned short* xs = (const unsigned short*)&xv;
  const unsigned short* gg = (const unsigned short*)&gv;
  uint4 ov; unsigned short* o = (unsigned short*)&ov;
#pragma unroll
  for (int j = 0; j < 8; ++j) o[j] = f2bf(bf2f(xs[j]) * bf2f(gg[j]));
  *(uint4*)(AI + ((row * 2) << 10) + col) = ov;
}

// ---------------- chunked selective scan over dbu (exp(-delta) precomputed) ----------------
__global__ void scan_a_kernel(const unsigned short* __restrict__ dbu,
                              const float* __restrict__ ea,
                              float* __restrict__ hend, float* __restrict__ P) {
  int blk = blockIdx.x;
  int b = blk / CHK, c = blk % CHK;
  int ch = threadIdx.x;
  size_t base = ((size_t)(b * N_ + c * TCH)) * DS_ + ch;
  const float* ep = ea + b * N_ + c * TCH;
  float h = 0.f, pa = 1.f;
#pragma unroll 4
  for (int t = 0; t < TCH; ++t) {
    float e = ep[t];
    h = e * h + bf2f(dbu[base + (size_t)t * DS_]);
    pa *= e;
  }
  hend[(size_t)blk * DS_ + ch] = h;
  if (ch == 0) P[blk] = pa;
}

__global__ void scan_combine_kernel(const float* __restrict__ hend, const float* __restrict__ P,
                                    float* __restrict__ carryin) {
  int b = blockIdx.x >> 2;
  int ch = (blockIdx.x & 3) * 256 + threadIdx.x;
  float carry = 0.f;
  for (int c = 0; c < CHK; ++c) {
    size_t o = (size_t)(b * CHK + c) * DS_ + ch;
    carryin[o] = carry;
    carry = P[b * CHK + c] * carry + hend[o];
  }
}

__global__ void scan_b_kernel(const unsigned short* __restrict__ dbu,
                              const float* __restrict__ ea,
                              const float* __restrict__ carryin,
                              unsigned short* __restrict__ y) {
  int blk = blockIdx.x;
  int b = blk / CHK, c = blk % CHK;
  int ch = threadIdx.x;
  size_t base = ((size_t)(b * N_ + c * TCH)) * DS_ + ch;
  const float* ep = ea + b * N_ + c * TCH;
  float h = carryin[(size_t)blk * DS_ + ch];
#pragma unroll 4
  for (int t = 0; t < TCH; ++t) {
    float e = ep[t];
    h = e * h + bf2f(dbu[base + (size_t)t * DS_]);
    y[base + (size_t)t * DS_] = f2bf(h);
  }
}

// ---------------- host ----------------
extern "C" void kernel_launch(void* const* d_in, const int* in_sizes, int n_in,
                              void* d_out, int out_size, void* d_ws, size_t ws_size,
                              hipStream_t stream) {
  const float* x       = (const float*)d_in[0];
  const float* n1w     = (const float*)d_in[1];
  const float* n1b     = (const float*)d_in[2];
  const float* gate_w  = (const float*)d_in[3];
  const float* gate_b  = (const float*)d_in[4];
  const float* state_w = (const float*)d_in[5];
  const float* state_b = (const float*)d_in[6];
  const float* out_w   = (const float*)d_in[7];
  const float* out_b   = (const float*)d_in[8];
  const float* n2w     = (const float*)d_in[9];
  const float* n2b     = (const float*)d_in[10];
  const float* mlp_w1  = (const float*)d_in[11];
  const float* mlp_b1  = (const float*)d_in[12];
  const float* mlp_w2  = (const float*)d_in[13];
  const float* mlp_b2  = (const float*)d_in[14];
  float* outp = (float*)d_out;

  char* w = (char*)d_ws;
  size_t off = 0;
  auto alloc = [&](size_t bytes) { char* p = w + off; off += (bytes + 255) & ~(size_t)255; return p; };

  unsigned short* gate_wT  = (unsigned short*)alloc((size_t)2048 * 1024 * 2);
  unsigned short* state_wT = (unsigned short*)alloc((size_t)1024 * 1024 * 2);
  unsigned short* out_wT   = (unsigned short*)alloc((size_t)1024 * 1024 * 2);
  unsigned short* w1T      = (unsigned short*)alloc((size_t)4096 * 1024 * 2);
  unsigned short* w2T      = (unsigned short*)alloc((size_t)1024 * 4096 * 2);
  float* swmean  = (float*)alloc(D_ * 4);
  float* sbmean  = (float*)alloc(256);
  float* delta   = (float*)alloc((size_t)ROWS * 4);
  float* eadel   = (float*)alloc((size_t)ROWS * 4);
  float* hend    = (float*)alloc((size_t)B_ * CHK * DS_ * 4);
  float* carryin = (float*)alloc((size_t)B_ * CHK * DS_ * 4);
  float* P       = (float*)alloc((size_t)B_ * CHK * 4);
  unsigned short* xn = (unsigned short*)alloc((size_t)ROWS * D_ * 2);      // later dbu
  unsigned short* gs = (unsigned short*)alloc((size_t)ROWS * HID_ * 2);    // gs1 head; later h1
  unsigned short* yx = (unsigned short*)alloc((size_t)ROWS * D_ * 2);      // y, then x2
  unsigned short* AI = (unsigned short*)alloc((size_t)2 * ROWS * D_ * 2);  // interleaved [xg;g2]; later x1b

  unsigned short* dbu = xn;   // written by state GEMM after xn fully consumed
  unsigned short* gs1 = gs;
  unsigned short* h1  = gs;
  unsigned short* y   = yx;
  unsigned short* x2  = yx;
  unsigned short* x1b = AI;   // bf16 residual stream; AI dead after state GEMM

  // prep
  means_kernel<<<D_ + 1, 256, 0, stream>>>(state_w, state_b, swmean, sbmean);
  transpose_all_kernel<<<12288, 256, 0, stream>>>(gate_w, state_w, out_w, mlp_w1, mlp_w2,
                                                  gate_wT, state_wT, out_wT, w1T, w2T);

  // LN1 + fused delta/exp(-delta)
  ln_kernel<true, false><<<ROWS, 256, 0, stream>>>(x, n1w, n1b, xn, swmean, sbmean, delta, eadel);

  const int BIG = 1 << 30;
  // gate GEMM EPI=8: gs1 = silu(g1); AI odd rows = silu(g2). (8192 x 2048 x 1024), 256 wgs
  gemm8p<256, 8><<<256, 512, 0, stream>>>(xn, 1024, BIG, xn, 1024,
                                          gate_wT, gate_b, gs1, nullptr, 2048, 1024, 8, AI);
  // AI even rows = xn * gs1
  ew_xg_kernel<<<(ROWS * D_) / 8 / 256, 256, 0, stream>>>(xn, gs1, AI);
  // state GEMM EPI=9: dbu[i] = delta[i]*u_i*bm_i from interleaved A. (16384 x 1024 x 1024), 256 wgs
  gemm8p<256, 9><<<256, 512, 0, stream>>>(AI, 1024, BIG, AI, 1024,
                                          state_wT, state_b, dbu, delta, 1024, 1024, 4, nullptr);

  // chunked scan over dbu
  scan_a_kernel<<<B_ * CHK, 1024, 0, stream>>>(dbu, eadel, hend, P);
  scan_combine_kernel<<<B_ * 4, 256, 0, stream>>>(hend, P, carryin);
  scan_b_kernel<<<B_ * CHK, 1024, 0, stream>>>(dbu, eadel, carryin, y);

  // ssm_out + residual -> x1b (bf16): (8192 x 1024 x 1024), BN=128 -> 256 wgs
  gemm8p<128, 6><<<256, 512, 0, stream>>>(y, 1024, BIG, y, 1024,
                                          out_wT, out_b, x1b, x, 1024, 1024, 8, nullptr);
  // LN2 (bf16 input)
  ln_kernel<false, true><<<ROWS, 256, 0, stream>>>(x1b, n2w, n2b, x2, nullptr, nullptr, nullptr, nullptr);
  // MLP up: (8192 x 4096 x 1024), 512 wgs
  gemm8p<256, 4><<<512, 512, 0, stream>>>(x2, 1024, BIG, x2, 1024,
                                          w1T, mlp_b1, h1, nullptr, 4096, 1024, 16, nullptr);
  // MLP down + residual(bf16) -> fp32 out: (8192 x 1024 x 4096), BN=128 -> 256 wgs
  gemm8p<128, 7><<<256, 512, 0, stream>>>(h1, 4096, BIG, h1, 4096,
                                          w2T, mlp_b2, outp, (const float*)x1b, 1024, 4096, 8, nullptr);
}